// Round 11
// baseline (220.032 us; speedup 1.0000x reference)
//
#include <hip/hip_runtime.h>

#define HID 64
#define IN_DIM 128
#define NXCD 8
#define JT 16            // j-tile width
#define NT (HID / JT)    // 4 tiles

// HW_REG_XCC_ID = 20, size 4 -> simm16 = 20 | ((4-1)<<11)
__device__ __forceinline__ int get_xcc() {
    return (int)(__builtin_amdgcn_s_getreg(20 | (3 << 11)) & (NXCD - 1));
}

// XCD-local atomics: global_atomic_add WITHOUT sc1 -> RMW resolves in the
// issuing XCD's L2, no 32B write-through to the device coherence point.
__device__ __forceinline__ void atomic_add_f32_xcd(float* p, float v) {
    asm volatile("global_atomic_add_f32 %0, %1, off" :: "v"(p), "v"(v) : "memory");
}
__device__ __forceinline__ void atomic_add_u32_xcd(int* p, int v) {
    asm volatile("global_atomic_add %0, %1, off" :: "v"(p), "v"(v) : "memory");
}

// ---------------- deg histogram: XCD-local atomics into per-XCD replica ----------------
__global__ __launch_bounds__(256) void k_deg(const int* __restrict__ dst,
                                             int* __restrict__ degR, int E, int Npad) {
    int* deg = degR + (size_t)get_xcc() * Npad;
    int t = blockIdx.x * blockDim.x + threadIdx.x;
    int e = t * 4;
    if (e + 3 < E) {
        int4 d4 = *(const int4*)(dst + e);
        atomic_add_u32_xcd(&deg[d4.x], 1);
        atomic_add_u32_xcd(&deg[d4.y], 1);
        atomic_add_u32_xcd(&deg[d4.z], 1);
        atomic_add_u32_xcd(&deg[d4.w], 1);
    } else {
        for (; e < E; ++e) atomic_add_u32_xcd(&deg[dst[e]], 1);
    }
}

// ---------------- dense: thread-per-node, j-tiled (4 x 16 acc), no LDS W tile ----------------
__global__ __launch_bounds__(256) void k_dense(const float* __restrict__ x,
                                               const float* __restrict__ W_in,
                                               const float* __restrict__ b_in,
                                               const float* __restrict__ W_g,
                                               const float* __restrict__ W_out,
                                               float* __restrict__ z, int N) {
    __shared__ float weff_l[HID];
    if (threadIdx.x < HID) {
        float s = 0.0f;
#pragma unroll
        for (int jp = 0; jp < HID; ++jp)
            s = fmaf(W_g[threadIdx.x * HID + jp], W_out[jp], s);
        weff_l[threadIdx.x] = s;
    }
    __syncthreads();

    int node = blockIdx.x * 256 + threadIdx.x;
    if (node >= N) node = N - 1;   // clamped threads duplicate-write identical values

    const float4* xrow = (const float4*)(x + (size_t)node * IN_DIM);
    float zv = 0.0f;

#pragma unroll
    for (int t = 0; t < NT; ++t) {
        float acc[JT];
#pragma unroll
        for (int jj = 0; jj < JT; ++jj)
            acc[jj] = b_in[t * JT + jj];     // uniform -> s_load

        for (int k4 = 0; k4 < IN_DIM / 4; ++k4) {
            float4 xv = xrow[k4];
            const float xk[4] = {xv.x, xv.y, xv.z, xv.w};
#pragma unroll
            for (int kk = 0; kk < 4; ++kk) {
                const float* wr = W_in + (k4 * 4 + kk) * HID + t * JT;  // wave-uniform
#pragma unroll
                for (int jj = 0; jj < JT; ++jj)
                    acc[jj] = fmaf(xk[kk], wr[jj], acc[jj]);
            }
        }
#pragma unroll
        for (int jj = 0; jj < JT; ++jj)
            zv = fmaf(fmaxf(acc[jj], 0.0f), weff_l[t * JT + jj], zv);
    }
    z[node] = zv;
}

// ---------------- dinv + zs: dinv = rsqrt(sum deg replicas + 1); zs = z*dinv ----------------
__global__ __launch_bounds__(256) void k_dinv(const int* __restrict__ degR,
                                              const float* __restrict__ z,
                                              float* __restrict__ dinv,
                                              float* __restrict__ zs,
                                              int N, int Npad) {
    int i = blockIdx.x * blockDim.x + threadIdx.x;
    if (i >= N) return;
    int d = 0;
#pragma unroll
    for (int r = 0; r < NXCD; ++r) d += degR[(size_t)r * Npad + i];
    float di = rsqrtf((float)d + 1.0f);
    dinv[i] = di;
    zs[i]   = z[i] * di;
}

// ---------------- scatter: 4 edges/thread, XCD-local atomics into per-XCD replica ----------
__global__ __launch_bounds__(256) void k_scatter(const int* __restrict__ eidx,
                                                 const float* __restrict__ zs,
                                                 float* __restrict__ accR,
                                                 int E, int Npad) {
    float* acc = accR + (size_t)get_xcc() * Npad;
    int t = blockIdx.x * blockDim.x + threadIdx.x;
    int e = t * 4;
    if (e + 3 < E) {
        int4 s4 = *(const int4*)(eidx + e);
        int4 d4 = *(const int4*)(eidx + E + e);
        float v0 = zs[s4.x], v1 = zs[s4.y], v2 = zs[s4.z], v3 = zs[s4.w];
        atomic_add_f32_xcd(&acc[d4.x], v0);
        atomic_add_f32_xcd(&acc[d4.y], v1);
        atomic_add_f32_xcd(&acc[d4.z], v2);
        atomic_add_f32_xcd(&acc[d4.w], v3);
    } else {
        for (; e < E; ++e) atomic_add_f32_xcd(&acc[eidx[E + e]], zs[eidx[e]]);
    }
}

// ------- final: out = dinv * (sum acc replicas + zs[self-loop]) + (b_g.W_out + b_out) -------
__global__ __launch_bounds__(256) void k_final(const float* __restrict__ dinv,
                                               const float* __restrict__ accR,
                                               const float* __restrict__ zs,
                                               const float* __restrict__ b_g,
                                               const float* __restrict__ W_out,
                                               const float* __restrict__ b_out,
                                               float* __restrict__ out, int N, int Npad) {
    const int lane = threadIdx.x & 63;
    float c = b_g[lane] * W_out[lane];
#pragma unroll
    for (int off = 32; off > 0; off >>= 1)
        c += __shfl_xor(c, off, 64);
    c += b_out[0];

    int i = blockIdx.x * blockDim.x + threadIdx.x;
    if (i >= N) return;
    float a = zs[i];   // self-loop
#pragma unroll
    for (int r = 0; r < NXCD; ++r) a += accR[(size_t)r * Npad + i];
    out[i] = fmaf(dinv[i], a, c);
}

// ---------------- launch ----------------

extern "C" void kernel_launch(void* const* d_in, const int* in_sizes, int n_in,
                              void* d_out, int out_size, void* d_ws, size_t ws_size,
                              hipStream_t stream) {
    const float* x     = (const float*)d_in[0];
    const int*   eidx  = (const int*)d_in[1];
    const float* W_in  = (const float*)d_in[2];
    const float* b_in  = (const float*)d_in[3];
    const float* W_g   = (const float*)d_in[4];
    const float* b_g   = (const float*)d_in[5];
    const float* W_out = (const float*)d_in[6];
    const float* b_out = (const float*)d_in[7];
    float* out = (float*)d_out;

    const int N = in_sizes[0] / IN_DIM;   // 100000
    const int E = in_sizes[1] / 2;        // 1600000

    // ws: degR[8*Npad] (int) | accR[8*Npad] | z[Npad] | dinv[Npad] | zs[Npad]
    const int Npad = (N + 63) & ~63;
    int*   degR = (int*)d_ws;
    float* accR = (float*)d_ws + (size_t)NXCD * Npad;
    float* z    = accR + (size_t)NXCD * Npad;
    float* dinv = z + Npad;
    float* zs   = dinv + Npad;

    hipMemsetAsync(degR, 0, (size_t)2 * NXCD * Npad * sizeof(int), stream);
    k_deg<<<(E / 4 + 255) / 256, 256, 0, stream>>>(eidx + E, degR, E, Npad);
    k_dense<<<(N + 255) / 256, 256, 0, stream>>>(x, W_in, b_in, W_g, W_out, z, N);
    k_dinv<<<(N + 255) / 256, 256, 0, stream>>>(degR, z, dinv, zs, N, Npad);
    k_scatter<<<(E / 4 + 255) / 256, 256, 0, stream>>>(eidx, zs, accR, E, Npad);
    k_final<<<(N + 255) / 256, 256, 0, stream>>>(dinv, accR, zs, b_g, W_out, b_out, out, N, Npad);
}

// Round 12
// 119.101 us; speedup vs baseline: 1.8474x; 1.8474x over previous
//
#include <hip/hip_runtime.h>

#define HID 64
#define IN_DIM 128
#define JT 16            // dense j-tile width
#define NT (HID / JT)
#define RANGE_BITS 14
#define RANGE (1 << RANGE_BITS)   // 16384 nodes per bucket (64 KB LDS)
#define NB 7                      // ceil(100000 / 16384)
#define MCH 36                    // edge chunks
#define SCAN_TPB 512

// ---------------- dense: thread-per-node, j-tiled, no global atomics ----------------
// z[node] = relu(x@W_in + b_in) . w_eff,  w_eff = W_g @ W_out
__global__ __launch_bounds__(256) void k_dense(const float* __restrict__ x,
                                               const float* __restrict__ W_in,
                                               const float* __restrict__ b_in,
                                               const float* __restrict__ W_g,
                                               const float* __restrict__ W_out,
                                               float* __restrict__ z, int N) {
    __shared__ float weff_l[HID];
    if (threadIdx.x < HID) {
        float s = 0.0f;
#pragma unroll
        for (int jp = 0; jp < HID; ++jp)
            s = fmaf(W_g[threadIdx.x * HID + jp], W_out[jp], s);
        weff_l[threadIdx.x] = s;
    }
    __syncthreads();

    int node = blockIdx.x * 256 + threadIdx.x;
    if (node >= N) node = N - 1;   // clamped threads duplicate-write identical values

    const float4* xrow = (const float4*)(x + (size_t)node * IN_DIM);
    float zv = 0.0f;

#pragma unroll
    for (int t = 0; t < NT; ++t) {
        float acc[JT];
#pragma unroll
        for (int jj = 0; jj < JT; ++jj)
            acc[jj] = b_in[t * JT + jj];     // uniform -> s_load

        for (int k4 = 0; k4 < IN_DIM / 4; ++k4) {
            float4 xv = xrow[k4];
            const float xk[4] = {xv.x, xv.y, xv.z, xv.w};
#pragma unroll
            for (int kk = 0; kk < 4; ++kk) {
                const float* wr = W_in + (k4 * 4 + kk) * HID + t * JT;  // wave-uniform
#pragma unroll
                for (int jj = 0; jj < JT; ++jj)
                    acc[jj] = fmaf(xk[kk], wr[jj], acc[jj]);
            }
        }
#pragma unroll
        for (int jj = 0; jj < JT; ++jj)
            zv = fmaf(fmaxf(acc[jj], 0.0f), weff_l[t * JT + jj], zv);
    }
    z[node] = zv;
}

// ---------------- pass A: binned degree count (LDS atomics only) ----------------
// block (r,m): scan edge chunk m, count dst in range r; write 64KB partial coalesced.
__global__ __launch_bounds__(SCAN_TPB) void k_binA(const int* __restrict__ dst,
                                                   int* __restrict__ part,
                                                   int E, int chunk) {
    __shared__ int cnt[RANGE];
    for (int i = threadIdx.x; i < RANGE; i += SCAN_TPB) cnt[i] = 0;
    __syncthreads();

    const int r = blockIdx.x % NB;
    const int lo = r << RANGE_BITS;
    const int e0 = (blockIdx.x / NB) * chunk;
    const int e1 = min(E, e0 + chunk);
    for (int e = e0 + (int)threadIdx.x * 4; e + 3 < e1; e += SCAN_TPB * 4) {
        int4 d4 = *(const int4*)(dst + e);
        unsigned v;
        v = (unsigned)(d4.x - lo); if (v < RANGE) atomicAdd(&cnt[v], 1);
        v = (unsigned)(d4.y - lo); if (v < RANGE) atomicAdd(&cnt[v], 1);
        v = (unsigned)(d4.z - lo); if (v < RANGE) atomicAdd(&cnt[v], 1);
        v = (unsigned)(d4.w - lo); if (v < RANGE) atomicAdd(&cnt[v], 1);
    }
    __syncthreads();

    int* outp = part + (size_t)blockIdx.x * RANGE;
    for (int i = threadIdx.x; i < RANGE; i += SCAN_TPB) outp[i] = cnt[i];
}

// ---------------- reduce deg -> dinv, zs = z * dinv ----------------
__global__ __launch_bounds__(256) void k_redDeg(const int* __restrict__ part,
                                                const float* __restrict__ z,
                                                float* __restrict__ dinv,
                                                float* __restrict__ zs, int N) {
    int i = blockIdx.x * blockDim.x + threadIdx.x;
    if (i >= N) return;
    const int r = i >> RANGE_BITS, idx = i & (RANGE - 1);
    int d = 0;
#pragma unroll 4
    for (int m = 0; m < MCH; ++m)
        d += part[((size_t)m * NB + r) * RANGE + idx];
    float di = rsqrtf((float)d + 1.0f);
    dinv[i] = di;
    zs[i]   = z[i] * di;
}

// ---------------- pass C: binned value scatter (LDS float atomics only) ----------------
__global__ __launch_bounds__(SCAN_TPB) void k_binC(const int* __restrict__ eidx,
                                                   const float* __restrict__ zs,
                                                   float* __restrict__ partf,
                                                   int E, int chunk) {
    __shared__ float acc[RANGE];
    for (int i = threadIdx.x; i < RANGE; i += SCAN_TPB) acc[i] = 0.0f;
    __syncthreads();

    const int r = blockIdx.x % NB;
    const int lo = r << RANGE_BITS;
    const int e0 = (blockIdx.x / NB) * chunk;
    const int e1 = min(E, e0 + chunk);
    for (int e = e0 + (int)threadIdx.x * 4; e + 3 < e1; e += SCAN_TPB * 4) {
        int4 s4 = *(const int4*)(eidx + e);        // src
        int4 d4 = *(const int4*)(eidx + E + e);    // dst
        unsigned v;
        v = (unsigned)(d4.x - lo); if (v < RANGE) atomicAdd(&acc[v], zs[s4.x]);
        v = (unsigned)(d4.y - lo); if (v < RANGE) atomicAdd(&acc[v], zs[s4.y]);
        v = (unsigned)(d4.z - lo); if (v < RANGE) atomicAdd(&acc[v], zs[s4.z]);
        v = (unsigned)(d4.w - lo); if (v < RANGE) atomicAdd(&acc[v], zs[s4.w]);
    }
    __syncthreads();

    float* outp = partf + (size_t)blockIdx.x * RANGE;
    for (int i = threadIdx.x; i < RANGE; i += SCAN_TPB) outp[i] = acc[i];
}

// ------- final: out = dinv * (sum partials + zs[self]) + (b_g.W_out + b_out) -------
__global__ __launch_bounds__(256) void k_redFinal(const float* __restrict__ partf,
                                                  const float* __restrict__ dinv,
                                                  const float* __restrict__ zs,
                                                  const float* __restrict__ b_g,
                                                  const float* __restrict__ W_out,
                                                  const float* __restrict__ b_out,
                                                  float* __restrict__ out, int N) {
    const int lane = threadIdx.x & 63;
    float c = b_g[lane] * W_out[lane];
#pragma unroll
    for (int off = 32; off > 0; off >>= 1)
        c += __shfl_xor(c, off, 64);
    c += b_out[0];

    int i = blockIdx.x * blockDim.x + threadIdx.x;
    if (i >= N) return;
    const int r = i >> RANGE_BITS, idx = i & (RANGE - 1);
    float a = zs[i];   // self-loop
#pragma unroll 4
    for (int m = 0; m < MCH; ++m)
        a += partf[((size_t)m * NB + r) * RANGE + idx];
    out[i] = fmaf(dinv[i], a, c);
}

// ---------------- launch ----------------

extern "C" void kernel_launch(void* const* d_in, const int* in_sizes, int n_in,
                              void* d_out, int out_size, void* d_ws, size_t ws_size,
                              hipStream_t stream) {
    const float* x     = (const float*)d_in[0];
    const int*   eidx  = (const int*)d_in[1];
    const float* W_in  = (const float*)d_in[2];
    const float* b_in  = (const float*)d_in[3];
    const float* W_g   = (const float*)d_in[4];
    const float* b_g   = (const float*)d_in[5];
    const float* W_out = (const float*)d_in[6];
    const float* b_out = (const float*)d_in[7];
    float* out = (float*)d_out;

    const int N = in_sizes[0] / IN_DIM;   // 100000
    const int E = in_sizes[1] / 2;        // 1600000

    // chunk: multiple of 4 covering E with MCH chunks
    const int chunk = (((E + MCH - 1) / MCH) + 3) & ~3;

    // ws layout: part[NB*MCH*RANGE] (int/float, reused) | z[N] | dinv[N] | zs[N]
    const size_t partElems = (size_t)NB * MCH * RANGE;
    int*   part  = (int*)d_ws;
    float* partf = (float*)d_ws;          // reused after k_redDeg consumed counts
    float* z     = (float*)d_ws + partElems;
    float* dinv  = z + N;
    float* zs    = dinv + N;

    k_binA<<<NB * MCH, SCAN_TPB, 0, stream>>>(eidx + E, part, E, chunk);
    k_dense<<<(N + 255) / 256, 256, 0, stream>>>(x, W_in, b_in, W_g, W_out, z, N);
    k_redDeg<<<(N + 255) / 256, 256, 0, stream>>>(part, z, dinv, zs, N);
    k_binC<<<NB * MCH, SCAN_TPB, 0, stream>>>(eidx, zs, partf, E, chunk);
    k_redFinal<<<(N + 255) / 256, 256, 0, stream>>>(partf, dinv, zs, b_g, W_out, b_out, out, N);
}